// Round 13
// baseline (174.898 us; speedup 1.0000x reference)
//
#include <hip/hip_runtime.h>
#include <hip/hip_fp16.h>
#include <math.h>

#define Hh 96
#define Ww 96
#define NPIX 9216
#define RAD 15
#define TAPS 31
#define NCH 144            // chunks of 64 sorted pixels
#define NBIN 4096
#define SPLIT 4            // blocks per j-group for buildK/matvec
#define EPSV 1e-20f
#define LOG2E 1.4426950408889634f
#define CUT2 42.0f         // box-box prune: exponent > 30 bits => k < 2^-30, safe

// ---- ws layout (4-byte units) ----
#define OFF_F    0                 // 8*NPIX feat_sorted: h0..h4, a, pad2
#define OFF_Q0   73728             // NPIX  q ping (original order, combine halo)
#define OFF_Q1   82944             // NPIX  q pong
#define OFF_QS   92160             // NPIX  q SORTED order (matvec input)
#define OFF_CBI  101376            // NPIX  bilateral colsum, SORTED order
#define OFF_BV   110592            // NPIX  bilateral q-filter, SORTED order
#define OFF_ROWW 119808            // 96
#define OFF_WTAB 119904            // 32
#define OFF_BBOX 119936            // NCH*12
// int regions
#define OFF_HIST 121664            // 4096
#define OFF_BASE 125760            // 4096
#define OFF_INV  129856            // NPIX  orig n -> sorted pos
#define OFF_SRT  139072            // NPIX  sorted pos -> orig n
#define OFF_OFS  148288            // NCH+1
#define OFF_WORK 148433            // NCH*NCH flat worklist (chunk ids, grouped by jg)
#define OFF_K    169984            // T*2048 u32: fp16 K blocks, [item][j][i]

__device__ __forceinline__ int color_key(float r, float g, float b){
  int rq = min(15, (int)r >> 4);
  int gq = min(15, (int)g >> 4);
  int bq = min(15, (int)b >> 4);
  int key = 0;
  #pragma unroll
  for (int k=0;k<4;k++){
    key |= ((rq>>k)&1) << (3*k+2);
    key |= ((gq>>k)&1) << (3*k+1);
    key |= ((bq>>k)&1) << (3*k);
  }
  return key;
}

// A: zero BV/CBI/hist + spatial tables
__global__ __launch_bounds__(256) void prepA_kernel(float* __restrict__ ws){
  int idx = blockIdx.x*256 + threadIdx.x;
  int* W = (int*)ws;
  if (idx < NPIX){ ws[OFF_BV+idx]=0.f; ws[OFF_CBI+idx]=0.f; }
  if (idx < NBIN) W[OFF_HIST+idx] = 0;
  if (blockIdx.x == 94 && threadIdx.x < Hh){
    int t = threadIdx.x;
    float s = 0.f;
    for (int yy=0; yy<Hh; ++yy){ float d=(float)(yy-t); s += expf(-d*d*(1.0f/18.0f)); }
    ws[OFF_ROWW + t] = s;                 // full 1-D colsum (spatial norm)
  }
  if (blockIdx.x == 95 && threadIdx.x < TAPS){
    int d = threadIdx.x - RAD;
    ws[OFF_WTAB + threadIdx.x] = expf(-(float)(d*d)*(1.0f/18.0f));
  }
}

// B: color histogram
__global__ __launch_bounds__(256) void prepB_kernel(const float* __restrict__ image,
                                                    float* __restrict__ ws){
  int n = blockIdx.x*256 + threadIdx.x;
  int key = color_key(image[n], image[NPIX+n], image[2*NPIX+n]);
  atomicAdd((int*)ws + OFF_HIST + key, 1);
}

// C: exclusive scan of 4096 bins (1 block)
__global__ __launch_bounds__(256) void prepC_kernel(float* __restrict__ ws){
  __shared__ int part[256];
  const int* hist = (const int*)ws + OFF_HIST;
  int* base = (int*)ws + OFF_BASE;
  int t = threadIdx.x;
  int loc[16]; int s = 0;
  #pragma unroll
  for (int i=0;i<16;i++){ loc[i]=s; s += hist[t*16+i]; }
  part[t] = s; __syncthreads();
  for (int off=1; off<256; off<<=1){
    int v = (t>=off) ? part[t-off] : 0;
    __syncthreads(); part[t] += v; __syncthreads();
  }
  int b = (t==0)?0:part[t-1];
  #pragma unroll
  for (int i=0;i<16;i++) base[t*16+i] = b + loc[i];
}

// D: scatter + sorted feature build + initial softmax q (orig + sorted)
__global__ __launch_bounds__(256) void prepD_kernel(const float* __restrict__ image,
                                                    const float* __restrict__ logits,
                                                    float* __restrict__ ws){
  int n = blockIdx.x*256 + threadIdx.x;
  int* W = (int*)ws;
  float r=image[n], g=image[NPIX+n], bl=image[2*NPIX+n];
  int key = color_key(r,g,bl);
  int pos = atomicAdd(W + OFF_BASE + key, 1);
  W[OFF_INV + n] = pos;
  W[OFF_SRT + pos] = n;
  int y=n/Ww, x=n%Ww;
  const float c=0.7213475205f;    // 0.5/ln2
  const float sc=1.2011224088f;   // sqrt(2c)
  float f0=(float)y*(1.f/160.f), f1=(float)x*(1.f/160.f);
  float f2=r*(1.f/3.f), f3=g*(1.f/3.f), f4=bl*(1.f/3.f);
  float a=c*(f0*f0+f1*f1+f2*f2+f3*f3+f4*f4);
  float q = 1.f/(1.f + __builtin_amdgcn_exp2f((logits[NPIX+n]-logits[n])*LOG2E));
  float* F = ws + OFF_F + (size_t)pos*8;
  F[0]=sc*f0; F[1]=sc*f1; F[2]=sc*f2; F[3]=sc*f3; F[4]=sc*f4;
  F[5]=a; F[6]=0.f; F[7]=0.f;
  ws[OFF_Q0 + n] = q;
  ws[OFF_QS + pos] = q;
}

// E1: per-chunk 5-D bbox, one wave per chunk
__global__ __launch_bounds__(256) void prepE1_kernel(float* __restrict__ ws){
  const int lane = threadIdx.x & 63, wid = threadIdx.x >> 6;
  int ch = blockIdx.x*4 + wid;
  if (ch >= NCH) return;
  const float* Fp = ws + OFF_F + ((size_t)ch*64 + lane)*8;
  float4 A = *(const float4*)Fp;
  float4 B4 = *(const float4*)(Fp+4);
  float mn[5]={A.x,A.y,A.z,A.w,B4.x}, mx[5]={A.x,A.y,A.z,A.w,B4.x};
  #pragma unroll
  for (int m=32; m; m>>=1){
    #pragma unroll
    for (int d=0;d<5;d++){
      mn[d]=fminf(mn[d], __shfl_xor(mn[d], m));
      mx[d]=fmaxf(mx[d], __shfl_xor(mx[d], m));
    }
  }
  if (lane == 0){
    float* bb = ws + OFF_BBOX + ch*12;
    #pragma unroll
    for (int d=0;d<5;d++){ bb[d]=mn[d]; bb[5+d]=mx[d]; }
  }
}

// E2: cull (box-box) + scan + pack flat worklist (1 block, all LDS)
__global__ __launch_bounds__(256) void prepE2_kernel(float* __restrict__ ws){
  __shared__ float bbl[NCH*12];
  __shared__ int part[256];
  __shared__ int cnt[NCH];
  const int t = threadIdx.x, lane = t & 63, wid = t >> 6;
  int* W = (int*)ws;

  for (int i=t; i<NCH*12; i+=256) bbl[i] = ws[OFF_BBOX + i];
  __syncthreads();

  for (int jg = wid; jg < NCH; jg += 4){
    const float* jb = &bbl[jg*12];
    int base = 0;
    #pragma unroll
    for (int r2=0;r2<3;r2++){
      int c2 = lane + 64*r2;
      bool sv = false;
      if (c2 < NCH){
        const float* cb = &bbl[c2*12];
        float s2 = 0.f;
        #pragma unroll
        for (int d=0;d<5;d++){
          float gap = fmaxf(0.f, fmaxf(cb[d]-jb[5+d], jb[d]-cb[5+d]));
          s2 = fmaf(gap, gap, s2);
        }
        sv = (s2 <= CUT2);
      }
      base += __popcll(__ballot(sv));
    }
    if (lane == 0) cnt[jg] = base;
  }
  __syncthreads();

  int v = (t < NCH) ? cnt[t] : 0;
  part[t] = v; __syncthreads();
  for (int off=1; off<256; off<<=1){
    int u = (t>=off) ? part[t-off] : 0;
    __syncthreads(); part[t] += u; __syncthreads();
  }
  if (t == 0) W[OFF_OFS] = 0;
  if (t < NCH) W[OFF_OFS + t + 1] = part[t];
  __syncthreads();

  for (int jg = wid; jg < NCH; jg += 4){
    const float* jb = &bbl[jg*12];
    int base = (jg == 0) ? 0 : part[jg-1];
    #pragma unroll
    for (int r2=0;r2<3;r2++){
      int c2 = lane + 64*r2;
      bool sv = false;
      if (c2 < NCH){
        const float* cb = &bbl[c2*12];
        float s2 = 0.f;
        #pragma unroll
        for (int d=0;d<5;d++){
          float gap = fmaxf(0.f, fmaxf(cb[d]-jb[5+d], jb[d]-cb[5+d]));
          s2 = fmaf(gap, gap, s2);
        }
        sv = (s2 <= CUT2);
      }
      unsigned long long m = __ballot(sv);
      if (sv){
        int pos = __popcll(m & ((1ull<<lane)-1ull));
        W[OFF_WORK + base + pos] = c2;       // jg implicit via OFS grouping
      }
      base += __popcll(m);
    }
  }
}

// buildK: block = (jg, sub). Wave loads j-features ONCE, then streams its
// items (stride 16 within the jg's contiguous worklist run): stage chunk,
// compute k (2 exp chains), pack fp16 K[item][j][i], accumulate aB/aC across
// items, single per-wave atomic commit (sorted order, coalesced).
__global__ __launch_bounds__(256) void buildK_kernel(float* __restrict__ ws){
  __shared__ float chunk[4][512];
  __shared__ float qsh[4][64];
  const int lane = threadIdx.x & 63, wid = threadIdx.x >> 6;
  const int jg = blockIdx.x / SPLIT, sub = blockIdx.x % SPLIT;
  int* W = (int*)ws;
  const int b0 = W[OFF_OFS + jg], e0 = W[OFF_OFS + jg + 1];
  const int* work = W + OFF_WORK;
  const float* F  = ws + OFF_F;
  float* s = &chunk[wid][0];
  float* ql = &qsh[wid][0];

  const int js = jg*64 + lane;
  float4 A  = *(const float4*)(F + (size_t)js*8);
  float4 B4 = *(const float4*)(F + (size_t)js*8 + 4);
  const float h0=A.x,h1=A.y,h2=A.z,h3=A.w,h4=B4.x,na=-B4.y;

  float aB=0.f, aC=0.f;
  for (int it = b0 + sub*4 + wid; it < e0; it += 16){
    int c = work[it];
    const float* src = F + (size_t)c*512;
    *(float4*)(s + lane*8)     = *(const float4*)(src + lane*8);
    *(float4*)(s + lane*8 + 4) = *(const float4*)(src + lane*8 + 4);
    ql[lane] = ws[OFF_QS + c*64 + lane];

    unsigned int kp[32];
    #pragma unroll 4
    for (int ii=0; ii<32; ii++){
      float4 w0 = *(const float4*)(s + 2*ii*8);
      float4 w1 = *(const float4*)(s + 2*ii*8 + 4);
      float e0v = na - w1.y;
      e0v=fmaf(h0,w0.x,e0v); e0v=fmaf(h1,w0.y,e0v); e0v=fmaf(h2,w0.z,e0v);
      e0v=fmaf(h3,w0.w,e0v); e0v=fmaf(h4,w1.x,e0v);
      float k0 = __builtin_amdgcn_exp2f(e0v);
      float4 u0 = *(const float4*)(s + (2*ii+1)*8);
      float4 u1 = *(const float4*)(s + (2*ii+1)*8 + 4);
      float e1v = na - u1.y;
      e1v=fmaf(h0,u0.x,e1v); e1v=fmaf(h1,u0.y,e1v); e1v=fmaf(h2,u0.z,e1v);
      e1v=fmaf(h3,u0.w,e1v); e1v=fmaf(h4,u1.x,e1v);
      float k1 = __builtin_amdgcn_exp2f(e1v);
      aC += k0 + k1;
      aB = fmaf(k0, ql[2*ii],   aB);
      aB = fmaf(k1, ql[2*ii+1], aB);
      __half2 h2v = __floats2half2_rn(k0, k1);
      kp[ii] = *reinterpret_cast<unsigned int*>(&h2v);
    }
    unsigned int* Kp = (unsigned int*)ws + OFF_K + (size_t)it*2048 + lane*32;
    #pragma unroll
    for (int r=0;r<8;r++)
      *(uint4*)(Kp + r*4) = make_uint4(kp[4*r],kp[4*r+1],kp[4*r+2],kp[4*r+3]);
  }
  atomicAdd(ws + OFF_BV  + js, aB);
  atomicAdd(ws + OFF_CBI + js, aC);
}

// matvec: same decomposition; streams sequential fp16 K slabs, q from LDS,
// register accumulate across items, one per-wave atomic commit.
__global__ __launch_bounds__(256) void matvec_kernel(float* __restrict__ ws){
  __shared__ float qsh[4][64];
  const int lane = threadIdx.x & 63, wid = threadIdx.x >> 6;
  const int jg = blockIdx.x / SPLIT, sub = blockIdx.x % SPLIT;
  const int* W = (const int*)ws;
  const int b0 = W[OFF_OFS + jg], e0 = W[OFF_OFS + jg + 1];
  const int* work = W + OFF_WORK;
  float* ql = &qsh[wid][0];
  const int js = jg*64 + lane;

  float acc0=0.f, acc1=0.f;
  for (int it = b0 + sub*4 + wid; it < e0; it += 16){
    int c = work[it];
    ql[lane] = ws[OFF_QS + c*64 + lane];
    const unsigned int* Kp = (const unsigned int*)ws + OFF_K + (size_t)it*2048 + lane*32;
    #pragma unroll
    for (int r=0;r<8;r++){
      uint4 p = *(const uint4*)(Kp + r*4);
      float4 qa = *(const float4*)(ql + r*8);
      float4 qb = *(const float4*)(ql + r*8 + 4);
      __half2 h;
      h = *reinterpret_cast<__half2*>(&p.x);
      acc0 = fmaf(__low2float(h), qa.x, acc0); acc1 = fmaf(__high2float(h), qa.y, acc1);
      h = *reinterpret_cast<__half2*>(&p.y);
      acc0 = fmaf(__low2float(h), qa.z, acc0); acc1 = fmaf(__high2float(h), qa.w, acc1);
      h = *reinterpret_cast<__half2*>(&p.z);
      acc0 = fmaf(__low2float(h), qb.x, acc0); acc1 = fmaf(__high2float(h), qb.y, acc1);
      h = *reinterpret_cast<__half2*>(&p.w);
      acc0 = fmaf(__low2float(h), qb.z, acc0); acc1 = fmaf(__high2float(h), qb.w, acc1);
    }
  }
  atomicAdd(ws + OFF_BV + js, acc0 + acc1);
}

// combine: separable spatial conv + message/compat/update + next-iter q.
__global__ __launch_bounds__(256) void combine_kernel(const float* __restrict__ logits,
                                                      const float* __restrict__ Wsp,
                                                      const float* __restrict__ Wbi,
                                                      const float* __restrict__ Cm,
                                                      float* __restrict__ ws,
                                                      float* __restrict__ out,
                                                      const float* __restrict__ qsrc,
                                                      float* __restrict__ qdst){
  __shared__ float tq[46][48];
  __shared__ float tr[46][17];
  __shared__ float wt[TAPS];
  int tx = threadIdx.x & 15, ty = threadIdx.x >> 4;
  int bx = blockIdx.x % 6, by = blockIdx.x / 6;
  int x0 = bx*16, y0 = by*16;

  for (int idx = threadIdx.x; idx < 46*46; idx += 256){
    int ly = idx / 46, lx = idx % 46;
    int gy = y0 - RAD + ly, gx = x0 - RAD + lx;
    float v = 0.f;
    if (gy >= 0 && gy < Hh && gx >= 0 && gx < Ww) v = qsrc[gy*Ww + gx];
    tq[ly][lx] = v;
  }
  if (threadIdx.x < TAPS) wt[threadIdx.x] = ws[OFF_WTAB + threadIdx.x];
  __syncthreads();

  for (int idx = threadIdx.x; idx < 46*16; idx += 256){
    int ly = idx >> 4, lx = idx & 15;
    float in = 0.f;
    #pragma unroll
    for (int dx=0; dx<TAPS; dx++) in = fmaf(wt[dx], tq[ly][lx+dx], in);
    tr[ly][lx] = in;
  }
  __syncthreads();

  int y = y0 + ty, x = x0 + tx, j = y*Ww + x;
  float S = 0.f;
  #pragma unroll
  for (int dy=0; dy<TAPS; dy++) S = fmaf(wt[dy], tr[ty+dy][tx], S);

  int js = ((const int*)ws)[OFF_INV + j];
  float Bv = ws[OFF_BV + js];
  ws[OFF_BV + js] = 0.f;                      // reset for next iteration's atomics
  float Cb = ws[OFF_CBI + js];
  float nb  = 1.0f/(Cb + EPSV);
  float Csp = ws[OFF_ROWW + y] * ws[OFF_ROWW + x];
  float nsp = 1.0f/(Csp + EPSV);

  float sp0 = S*nsp,  sp1 = (Csp - S)*nsp;    // q1 = 1 - q0 identity
  float bi0 = Bv*nb,  bi1 = (Cb - Bv)*nb;

  float m0 = Wsp[0]*sp0 + Wsp[1]*sp1 + Wbi[0]*bi0 + Wbi[1]*bi1;
  float m1 = Wsp[2]*sp0 + Wsp[3]*sp1 + Wbi[2]*bi0 + Wbi[3]*bi1;
  float cm0 = Cm[0]*m0 + Cm[1]*m1;
  float cm1 = Cm[2]*m0 + Cm[3]*m1;

  float o0 = logits[j]        - cm0;
  float o1 = logits[NPIX + j] - cm1;
  out[j]        = o0;
  out[NPIX + j] = o1;

  float qn = 1.0f / (1.0f + __builtin_amdgcn_exp2f((o1-o0)*LOG2E));
  qdst[j] = qn;
  ws[OFF_QS + js] = qn;
}

extern "C" void kernel_launch(void* const* d_in, const int* in_sizes, int n_in,
                              void* d_out, int out_size, void* d_ws, size_t ws_size,
                              hipStream_t stream){
  const float* image  = (const float*)d_in[0];
  const float* logits = (const float*)d_in[1];
  const float* Wsp    = (const float*)d_in[2];
  const float* Wbi    = (const float*)d_in[3];
  const float* Cm     = (const float*)d_in[4];
  float* out = (float*)d_out;
  float* ws  = (float*)d_ws;

  float* qbuf[2] = { ws + OFF_Q0, ws + OFF_Q1 };

  prepA_kernel <<<96, 256, 0, stream>>>(ws);
  prepB_kernel <<<36, 256, 0, stream>>>(image, ws);
  prepC_kernel <<<1, 256, 0, stream>>>(ws);
  prepD_kernel <<<36, 256, 0, stream>>>(image, logits, ws);
  prepE1_kernel<<<36, 256, 0, stream>>>(ws);
  prepE2_kernel<<<1, 256, 0, stream>>>(ws);

  // iteration 0: build fp16 K + colsum + q-filter in one pass
  buildK_kernel<<<NCH*SPLIT, 256, 0, stream>>>(ws);
  combine_kernel<<<36, 256, 0, stream>>>(logits, Wsp, Wbi, Cm, ws, out,
                                         qbuf[0], qbuf[1]);
  // iterations 1..4: stream K
  for (int t=1; t<5; ++t){
    matvec_kernel<<<NCH*SPLIT, 256, 0, stream>>>(ws);
    combine_kernel<<<36, 256, 0, stream>>>(logits, Wsp, Wbi, Cm, ws, out,
                                           qbuf[t&1], qbuf[(t+1)&1]);
  }
}

// Round 14
// 157.082 us; speedup vs baseline: 1.1134x; 1.1134x over previous
//
#include <hip/hip_runtime.h>
#include <hip/hip_fp16.h>
#include <math.h>

#define Hh 96
#define Ww 96
#define NPIX 9216
#define RAD 15
#define TAPS 31
#define NCH 144            // chunks of 64 sorted pixels
#define NBIN 4096
#define GRIDK 256          // buildK blocks (1024 waves, ~2-3 items each)
#define GRIDM 256          // matvec blocks
#define EPSV 1e-20f
#define LOG2E 1.4426950408889634f
#define CUT2 42.0f         // box-box prune: k < 2^-30 beyond => safe (err ~1e-5)

// ---- ws layout (4-byte units) ----
#define OFF_F    0                 // 8*NPIX feat_sorted: h0..h4, a, q, pad
#define OFF_Q0   73728             // NPIX  q ping (original order, combine halo)
#define OFF_Q1   82944             // NPIX  q pong
#define OFF_QS   92160             // NPIX  q SORTED order (matvec input)
#define OFF_CBI  101376            // NPIX  bilateral colsum, SORTED order
#define OFF_BV   110592            // NPIX  bilateral q-filter, SORTED order
#define OFF_ROWW 119808            // 96
#define OFF_WTAB 119904            // 32
#define OFF_BBOX 119936            // NCH*12
// int regions
#define OFF_HIST 121664            // 4096
#define OFF_BASE 125760            // 4096
#define OFF_INV  129856            // NPIX  orig n -> sorted pos
#define OFF_SRT  139072            // NPIX  sorted pos -> orig n
#define OFF_OFS  148288            // NCH+1
#define OFF_WORK 148433            // NCH*NCH flat worklist (jg<<8|c)
#define OFF_K    169984            // T*2048 u32: fp16 K blocks, [item][j][i]

__device__ __forceinline__ int color_key(float r, float g, float b){
  int rq = min(15, (int)r >> 4);
  int gq = min(15, (int)g >> 4);
  int bq = min(15, (int)b >> 4);
  int key = 0;
  #pragma unroll
  for (int k=0;k<4;k++){
    key |= ((rq>>k)&1) << (3*k+2);
    key |= ((gq>>k)&1) << (3*k+1);
    key |= ((bq>>k)&1) << (3*k);
  }
  return key;
}

// A: zero BV/CBI/hist + spatial tables
__global__ __launch_bounds__(256) void prepA_kernel(float* __restrict__ ws){
  int idx = blockIdx.x*256 + threadIdx.x;
  int* W = (int*)ws;
  if (idx < NPIX){ ws[OFF_BV+idx]=0.f; ws[OFF_CBI+idx]=0.f; }
  if (idx < NBIN) W[OFF_HIST+idx] = 0;
  if (blockIdx.x == 94 && threadIdx.x < Hh){
    int t = threadIdx.x;
    float s = 0.f;
    for (int yy=0; yy<Hh; ++yy){ float d=(float)(yy-t); s += expf(-d*d*(1.0f/18.0f)); }
    ws[OFF_ROWW + t] = s;                 // full 1-D colsum (spatial norm)
  }
  if (blockIdx.x == 95 && threadIdx.x < TAPS){
    int d = threadIdx.x - RAD;
    ws[OFF_WTAB + threadIdx.x] = expf(-(float)(d*d)*(1.0f/18.0f));
  }
}

// B: color histogram
__global__ __launch_bounds__(256) void prepB_kernel(const float* __restrict__ image,
                                                    float* __restrict__ ws){
  int n = blockIdx.x*256 + threadIdx.x;
  int key = color_key(image[n], image[NPIX+n], image[2*NPIX+n]);
  atomicAdd((int*)ws + OFF_HIST + key, 1);
}

// C: exclusive scan of 4096 bins (1 block)
__global__ __launch_bounds__(256) void prepC_kernel(float* __restrict__ ws){
  __shared__ int part[256];
  const int* hist = (const int*)ws + OFF_HIST;
  int* base = (int*)ws + OFF_BASE;
  int t = threadIdx.x;
  int loc[16]; int s = 0;
  #pragma unroll
  for (int i=0;i<16;i++){ loc[i]=s; s += hist[t*16+i]; }
  part[t] = s; __syncthreads();
  for (int off=1; off<256; off<<=1){
    int v = (t>=off) ? part[t-off] : 0;
    __syncthreads(); part[t] += v; __syncthreads();
  }
  int b = (t==0)?0:part[t-1];
  #pragma unroll
  for (int i=0;i<16;i++) base[t*16+i] = b + loc[i];
}

// D: scatter + sorted feature build (q in F slot 6) + initial q (orig + sorted)
__global__ __launch_bounds__(256) void prepD_kernel(const float* __restrict__ image,
                                                    const float* __restrict__ logits,
                                                    float* __restrict__ ws){
  int n = blockIdx.x*256 + threadIdx.x;
  int* W = (int*)ws;
  float r=image[n], g=image[NPIX+n], bl=image[2*NPIX+n];
  int key = color_key(r,g,bl);
  int pos = atomicAdd(W + OFF_BASE + key, 1);
  W[OFF_INV + n] = pos;
  W[OFF_SRT + pos] = n;
  int y=n/Ww, x=n%Ww;
  const float c=0.7213475205f;    // 0.5/ln2
  const float sc=1.2011224088f;   // sqrt(2c)
  float f0=(float)y*(1.f/160.f), f1=(float)x*(1.f/160.f);
  float f2=r*(1.f/3.f), f3=g*(1.f/3.f), f4=bl*(1.f/3.f);
  float a=c*(f0*f0+f1*f1+f2*f2+f3*f3+f4*f4);
  float q = 1.f/(1.f + __builtin_amdgcn_exp2f((logits[NPIX+n]-logits[n])*LOG2E));
  float* F = ws + OFF_F + (size_t)pos*8;
  F[0]=sc*f0; F[1]=sc*f1; F[2]=sc*f2; F[3]=sc*f3; F[4]=sc*f4;
  F[5]=a; F[6]=q; F[7]=0.f;
  ws[OFF_Q0 + n] = q;
  ws[OFF_QS + pos] = q;
}

// E1: per-chunk 5-D bbox, one wave per chunk
__global__ __launch_bounds__(256) void prepE1_kernel(float* __restrict__ ws){
  const int lane = threadIdx.x & 63, wid = threadIdx.x >> 6;
  int ch = blockIdx.x*4 + wid;
  if (ch >= NCH) return;
  const float* Fp = ws + OFF_F + ((size_t)ch*64 + lane)*8;
  float4 A = *(const float4*)Fp;
  float4 B4 = *(const float4*)(Fp+4);
  float mn[5]={A.x,A.y,A.z,A.w,B4.x}, mx[5]={A.x,A.y,A.z,A.w,B4.x};
  #pragma unroll
  for (int m=32; m; m>>=1){
    #pragma unroll
    for (int d=0;d<5;d++){
      mn[d]=fminf(mn[d], __shfl_xor(mn[d], m));
      mx[d]=fmaxf(mx[d], __shfl_xor(mx[d], m));
    }
  }
  if (lane == 0){
    float* bb = ws + OFF_BBOX + ch*12;
    #pragma unroll
    for (int d=0;d<5;d++){ bb[d]=mn[d]; bb[5+d]=mx[d]; }
  }
}

// E2: cull (box-box) + scan + pack flat worklist (1 block, all LDS)
__global__ __launch_bounds__(256) void prepE2_kernel(float* __restrict__ ws){
  __shared__ float bbl[NCH*12];
  __shared__ int part[256];
  __shared__ int cnt[NCH];
  const int t = threadIdx.x, lane = t & 63, wid = t >> 6;
  int* W = (int*)ws;

  for (int i=t; i<NCH*12; i+=256) bbl[i] = ws[OFF_BBOX + i];
  __syncthreads();

  for (int jg = wid; jg < NCH; jg += 4){
    const float* jb = &bbl[jg*12];
    int base = 0;
    #pragma unroll
    for (int r2=0;r2<3;r2++){
      int c2 = lane + 64*r2;
      bool sv = false;
      if (c2 < NCH){
        const float* cb = &bbl[c2*12];
        float s2 = 0.f;
        #pragma unroll
        for (int d=0;d<5;d++){
          float gap = fmaxf(0.f, fmaxf(cb[d]-jb[5+d], jb[d]-cb[5+d]));
          s2 = fmaf(gap, gap, s2);
        }
        sv = (s2 <= CUT2);
      }
      base += __popcll(__ballot(sv));
    }
    if (lane == 0) cnt[jg] = base;
  }
  __syncthreads();

  int v = (t < NCH) ? cnt[t] : 0;
  part[t] = v; __syncthreads();
  for (int off=1; off<256; off<<=1){
    int u = (t>=off) ? part[t-off] : 0;
    __syncthreads(); part[t] += u; __syncthreads();
  }
  if (t == 0) W[OFF_OFS] = 0;
  if (t < NCH) W[OFF_OFS + t + 1] = part[t];
  __syncthreads();

  for (int jg = wid; jg < NCH; jg += 4){
    const float* jb = &bbl[jg*12];
    int base = (jg == 0) ? 0 : part[jg-1];
    #pragma unroll
    for (int r2=0;r2<3;r2++){
      int c2 = lane + 64*r2;
      bool sv = false;
      if (c2 < NCH){
        const float* cb = &bbl[c2*12];
        float s2 = 0.f;
        #pragma unroll
        for (int d=0;d<5;d++){
          float gap = fmaxf(0.f, fmaxf(cb[d]-jb[5+d], jb[d]-cb[5+d]));
          s2 = fmaf(gap, gap, s2);
        }
        sv = (s2 <= CUT2);
      }
      unsigned long long m = __ballot(sv);
      if (sv){
        int pos = __popcll(m & ((1ull<<lane)-1ull));
        W[OFF_WORK + base + pos] = (jg<<8) | c2;
      }
      base += __popcll(m);
    }
  }
}

// buildK: 1024 waves, each owns a contiguous item segment, 2-deep pipelined:
// item n+1's global loads issue during item n's compute. q_i from staged w1.z.
// Packs fp16 K[item][j][i]; per-item coalesced atomics into sorted BV/CBI.
__global__ __launch_bounds__(256) void buildK_kernel(float* __restrict__ ws){
  __shared__ float chunk[4][512];
  const int lane = threadIdx.x & 63, wid = threadIdx.x >> 6;
  int* W = (int*)ws;
  const int T = W[OFF_OFS + NCH];
  const int* work = W + OFF_WORK;
  const float* F  = ws + OFF_F;
  float* s = &chunk[wid][0];
  const int NW = GRIDK*4;
  const int wv = blockIdx.x*4 + wid;
  const int seg = (T + NW - 1)/NW;
  int it = wv*seg;
  const int itEnd = min(T, it + seg);
  if (it >= itEnd) return;

  // prologue: item `it`
  int en = work[it];
  int c = en & 255;
  float4 rA = *(const float4*)(F + (size_t)c*512 + lane*8);
  float4 rB = *(const float4*)(F + (size_t)c*512 + lane*8 + 4);
  int js = (en >> 8)*64 + lane;
  float4 jA = *(const float4*)(F + (size_t)js*8);
  float4 jB = *(const float4*)(F + (size_t)js*8 + 4);

  for (;;){
    *(float4*)(s + lane*8)     = rA;
    *(float4*)(s + lane*8 + 4) = rB;
    const float h0=jA.x,h1=jA.y,h2=jA.z,h3=jA.w,h4=jB.x,na=-jB.y;
    const int curIt = it, curJs = js;

    // prefetch next item (issues before compute; waits land after)
    int nit = it + 1;
    bool more = nit < itEnd;
    float4 nA, nB, njA, njB; int njs = 0;
    if (more){
      int en2 = work[nit];
      int c2 = en2 & 255;
      nA = *(const float4*)(F + (size_t)c2*512 + lane*8);
      nB = *(const float4*)(F + (size_t)c2*512 + lane*8 + 4);
      njs = (en2 >> 8)*64 + lane;
      njA = *(const float4*)(F + (size_t)njs*8);
      njB = *(const float4*)(F + (size_t)njs*8 + 4);
    }

    float aB=0.f, aC=0.f;
    unsigned int kp[32];
    #pragma unroll
    for (int ii=0; ii<32; ii++){          // FULL unroll: kp indices constant
      float4 w0 = *(const float4*)(s + 2*ii*8);
      float4 w1 = *(const float4*)(s + 2*ii*8 + 4);
      float e0 = na - w1.y;
      e0=fmaf(h0,w0.x,e0); e0=fmaf(h1,w0.y,e0); e0=fmaf(h2,w0.z,e0);
      e0=fmaf(h3,w0.w,e0); e0=fmaf(h4,w1.x,e0);
      float k0 = __builtin_amdgcn_exp2f(e0);
      float4 u0 = *(const float4*)(s + (2*ii+1)*8);
      float4 u1 = *(const float4*)(s + (2*ii+1)*8 + 4);
      float e1 = na - u1.y;
      e1=fmaf(h0,u0.x,e1); e1=fmaf(h1,u0.y,e1); e1=fmaf(h2,u0.z,e1);
      e1=fmaf(h3,u0.w,e1); e1=fmaf(h4,u1.x,e1);
      float k1 = __builtin_amdgcn_exp2f(e1);
      aC += k0 + k1;
      aB = fmaf(k0, w1.z, aB);            // q_i staged in slot 6
      aB = fmaf(k1, u1.z, aB);
      __half2 h2v = __floats2half2_rn(k0, k1);
      kp[ii] = *reinterpret_cast<unsigned int*>(&h2v);
    }
    unsigned int* Kp = (unsigned int*)ws + OFF_K + (size_t)curIt*2048 + lane*32;
    #pragma unroll
    for (int r=0;r<8;r++)
      *(uint4*)(Kp + r*4) = make_uint4(kp[4*r],kp[4*r+1],kp[4*r+2],kp[4*r+3]);
    atomicAdd(ws + OFF_BV  + curJs, aB);
    atomicAdd(ws + OFF_CBI + curJs, aC);

    if (!more) break;
    it = nit; js = njs; rA = nA; rB = nB; jA = njA; jB = njB;
  }
}

// matvec: same segment decomposition, 2-deep pipelined K/q prefetch.
// Named p0..p7 regs (no runtime-indexed arrays). Per-item coalesced atomic.
__global__ __launch_bounds__(256) void matvec_kernel(float* __restrict__ ws){
  __shared__ float qsh[4][64];
  const int lane = threadIdx.x & 63, wid = threadIdx.x >> 6;
  const int* W = (const int*)ws;
  const int T = W[OFF_OFS + NCH];
  const int* work = W + OFF_WORK;
  float* ql = &qsh[wid][0];
  const int NW = GRIDM*4;
  const int wv = blockIdx.x*4 + wid;
  const int seg = (T + NW - 1)/NW;
  int it = wv*seg;
  const int itEnd = min(T, it + seg);
  if (it >= itEnd) return;

  const unsigned int* Kbase = (const unsigned int*)ws + OFF_K;

  // prologue: item `it`
  int en = work[it];
  int c = en & 255;
  int js = (en >> 8)*64 + lane;
  float qv = ws[OFF_QS + c*64 + lane];
  const unsigned int* Kp = Kbase + (size_t)it*2048 + lane*32;
  uint4 p0 = *(const uint4*)(Kp);
  uint4 p1 = *(const uint4*)(Kp + 4);
  uint4 p2 = *(const uint4*)(Kp + 8);
  uint4 p3 = *(const uint4*)(Kp + 12);
  uint4 p4 = *(const uint4*)(Kp + 16);
  uint4 p5 = *(const uint4*)(Kp + 20);
  uint4 p6 = *(const uint4*)(Kp + 24);
  uint4 p7 = *(const uint4*)(Kp + 28);

  for (;;){
    ql[lane] = qv;
    const int curJs = js;

    // prefetch next item
    int nit = it + 1;
    bool more = nit < itEnd;
    float nqv = 0.f; int njs = 0;
    uint4 n0,n1,n2,n3,n4,n5,n6,n7;
    if (more){
      int en2 = work[nit];
      int c2 = en2 & 255;
      njs = (en2 >> 8)*64 + lane;
      nqv = ws[OFF_QS + c2*64 + lane];
      const unsigned int* Np = Kbase + (size_t)nit*2048 + lane*32;
      n0=*(const uint4*)(Np);    n1=*(const uint4*)(Np+4);
      n2=*(const uint4*)(Np+8);  n3=*(const uint4*)(Np+12);
      n4=*(const uint4*)(Np+16); n5=*(const uint4*)(Np+20);
      n6=*(const uint4*)(Np+24); n7=*(const uint4*)(Np+28);
    }

    float acc0=0.f, acc1=0.f;
    #define MV_STEP(P, R)                                                      \
    {                                                                          \
      float4 qa = *(const float4*)(ql + (R)*8);                                \
      float4 qb = *(const float4*)(ql + (R)*8 + 4);                            \
      __half2 h;                                                               \
      h = *reinterpret_cast<__half2*>(&P.x);                                   \
      acc0 = fmaf(__low2float(h), qa.x, acc0);                                 \
      acc1 = fmaf(__high2float(h), qa.y, acc1);                                \
      h = *reinterpret_cast<__half2*>(&P.y);                                   \
      acc0 = fmaf(__low2float(h), qa.z, acc0);                                 \
      acc1 = fmaf(__high2float(h), qa.w, acc1);                                \
      h = *reinterpret_cast<__half2*>(&P.z);                                   \
      acc0 = fmaf(__low2float(h), qb.x, acc0);                                 \
      acc1 = fmaf(__high2float(h), qb.y, acc1);                                \
      h = *reinterpret_cast<__half2*>(&P.w);                                   \
      acc0 = fmaf(__low2float(h), qb.z, acc0);                                 \
      acc1 = fmaf(__high2float(h), qb.w, acc1);                                \
    }
    MV_STEP(p0,0) MV_STEP(p1,1) MV_STEP(p2,2) MV_STEP(p3,3)
    MV_STEP(p4,4) MV_STEP(p5,5) MV_STEP(p6,6) MV_STEP(p7,7)
    #undef MV_STEP

    atomicAdd(ws + OFF_BV + curJs, acc0 + acc1);

    if (!more) break;
    it = nit; js = njs; qv = nqv;
    p0=n0; p1=n1; p2=n2; p3=n3; p4=n4; p5=n5; p6=n6; p7=n7;
  }
}

// combine: separable spatial conv + message/compat/update + next-iter q.
__global__ __launch_bounds__(256) void combine_kernel(const float* __restrict__ logits,
                                                      const float* __restrict__ Wsp,
                                                      const float* __restrict__ Wbi,
                                                      const float* __restrict__ Cm,
                                                      float* __restrict__ ws,
                                                      float* __restrict__ out,
                                                      const float* __restrict__ qsrc,
                                                      float* __restrict__ qdst){
  __shared__ float tq[46][48];
  __shared__ float tr[46][17];
  __shared__ float wt[TAPS];
  int tx = threadIdx.x & 15, ty = threadIdx.x >> 4;
  int bx = blockIdx.x % 6, by = blockIdx.x / 6;
  int x0 = bx*16, y0 = by*16;

  for (int idx = threadIdx.x; idx < 46*46; idx += 256){
    int ly = idx / 46, lx = idx % 46;
    int gy = y0 - RAD + ly, gx = x0 - RAD + lx;
    float v = 0.f;
    if (gy >= 0 && gy < Hh && gx >= 0 && gx < Ww) v = qsrc[gy*Ww + gx];
    tq[ly][lx] = v;
  }
  if (threadIdx.x < TAPS) wt[threadIdx.x] = ws[OFF_WTAB + threadIdx.x];
  __syncthreads();

  for (int idx = threadIdx.x; idx < 46*16; idx += 256){
    int ly = idx >> 4, lx = idx & 15;
    float in = 0.f;
    #pragma unroll
    for (int dx=0; dx<TAPS; dx++) in = fmaf(wt[dx], tq[ly][lx+dx], in);
    tr[ly][lx] = in;
  }
  __syncthreads();

  int y = y0 + ty, x = x0 + tx, j = y*Ww + x;
  float S = 0.f;
  #pragma unroll
  for (int dy=0; dy<TAPS; dy++) S = fmaf(wt[dy], tr[ty+dy][tx], S);

  int js = ((const int*)ws)[OFF_INV + j];
  float Bv = ws[OFF_BV + js];
  ws[OFF_BV + js] = 0.f;                      // reset for next iteration's atomics
  float Cb = ws[OFF_CBI + js];
  float nb  = 1.0f/(Cb + EPSV);
  float Csp = ws[OFF_ROWW + y] * ws[OFF_ROWW + x];
  float nsp = 1.0f/(Csp + EPSV);

  float sp0 = S*nsp,  sp1 = (Csp - S)*nsp;    // q1 = 1 - q0 identity
  float bi0 = Bv*nb,  bi1 = (Cb - Bv)*nb;

  float m0 = Wsp[0]*sp0 + Wsp[1]*sp1 + Wbi[0]*bi0 + Wbi[1]*bi1;
  float m1 = Wsp[2]*sp0 + Wsp[3]*sp1 + Wbi[2]*bi0 + Wbi[3]*bi1;
  float cm0 = Cm[0]*m0 + Cm[1]*m1;
  float cm1 = Cm[2]*m0 + Cm[3]*m1;

  float o0 = logits[j]        - cm0;
  float o1 = logits[NPIX + j] - cm1;
  out[j]        = o0;
  out[NPIX + j] = o1;

  float qn = 1.0f / (1.0f + __builtin_amdgcn_exp2f((o1-o0)*LOG2E));
  qdst[j] = qn;
  ws[OFF_QS + js] = qn;
}

extern "C" void kernel_launch(void* const* d_in, const int* in_sizes, int n_in,
                              void* d_out, int out_size, void* d_ws, size_t ws_size,
                              hipStream_t stream){
  const float* image  = (const float*)d_in[0];
  const float* logits = (const float*)d_in[1];
  const float* Wsp    = (const float*)d_in[2];
  const float* Wbi    = (const float*)d_in[3];
  const float* Cm     = (const float*)d_in[4];
  float* out = (float*)d_out;
  float* ws  = (float*)d_ws;

  float* qbuf[2] = { ws + OFF_Q0, ws + OFF_Q1 };

  prepA_kernel <<<96, 256, 0, stream>>>(ws);
  prepB_kernel <<<36, 256, 0, stream>>>(image, ws);
  prepC_kernel <<<1, 256, 0, stream>>>(ws);
  prepD_kernel <<<36, 256, 0, stream>>>(image, logits, ws);
  prepE1_kernel<<<36, 256, 0, stream>>>(ws);
  prepE2_kernel<<<1, 256, 0, stream>>>(ws);

  // iteration 0: build fp16 K + colsum + q-filter in one pass
  buildK_kernel<<<GRIDK, 256, 0, stream>>>(ws);
  combine_kernel<<<36, 256, 0, stream>>>(logits, Wsp, Wbi, Cm, ws, out,
                                         qbuf[0], qbuf[1]);
  // iterations 1..4: stream K
  for (int t=1; t<5; ++t){
    matvec_kernel<<<GRIDM, 256, 0, stream>>>(ws);
    combine_kernel<<<36, 256, 0, stream>>>(logits, Wsp, Wbi, Cm, ws, out,
                                           qbuf[t&1], qbuf[(t+1)&1]);
  }
}

// Round 15
// 156.943 us; speedup vs baseline: 1.1144x; 1.0009x over previous
//
#include <hip/hip_runtime.h>
#include <hip/hip_fp16.h>
#include <math.h>

#define Hh 96
#define Ww 96
#define NPIX 9216
#define RAD 15
#define TAPS 31
#define NCH 144            // chunks of 64 sorted pixels
#define NBIN 4096
#define GRIDK 256          // buildK blocks (1024 waves, ~2-3 items each)
#define GRIDM 256          // matvec blocks
#define EPSV 1e-20f
#define LOG2E 1.4426950408889634f
#define CUT2 42.0f         // box-box prune: k < 2^-30 beyond => safe (err ~1e-5)

// ---- ws layout (4-byte units) ----
#define OFF_F    0                 // 8*NPIX feat_sorted: h0..h4, a, q, pad
#define OFF_Q0   73728             // NPIX  q ping (original order, combine halo)
#define OFF_Q1   82944             // NPIX  q pong
#define OFF_QS   92160             // NPIX  q SORTED order (matvec input)
#define OFF_CBI  101376            // NPIX  bilateral colsum, SORTED order
#define OFF_BV   110592            // NPIX  bilateral q-filter, SORTED order
#define OFF_ROWW 119808            // 96
#define OFF_WTAB 119904            // 32
#define OFF_BBOX 119936            // NCH*12
// int regions
#define OFF_HIST 121664            // 4096
#define OFF_BASE 125760            // 4096
#define OFF_INV  129856            // NPIX  orig n -> sorted pos
#define OFF_SRT  139072            // NPIX  sorted pos -> orig n
#define OFF_OFS  148288            // NCH+1
#define OFF_WORK 148433            // NCH*NCH flat worklist (jg<<8|c)
#define OFF_K    169984            // T*2048 u32: fp16 K blocks, [item][j][i]

__device__ __forceinline__ int color_key(float r, float g, float b){
  int rq = min(15, (int)r >> 4);
  int gq = min(15, (int)g >> 4);
  int bq = min(15, (int)b >> 4);
  int key = 0;
  #pragma unroll
  for (int k=0;k<4;k++){
    key |= ((rq>>k)&1) << (3*k+2);
    key |= ((gq>>k)&1) << (3*k+1);
    key |= ((bq>>k)&1) << (3*k);
  }
  return key;
}

// A: zero BV/CBI/hist + spatial tables
__global__ __launch_bounds__(256) void prepA_kernel(float* __restrict__ ws){
  int idx = blockIdx.x*256 + threadIdx.x;
  int* W = (int*)ws;
  if (idx < NPIX){ ws[OFF_BV+idx]=0.f; ws[OFF_CBI+idx]=0.f; }
  if (idx < NBIN) W[OFF_HIST+idx] = 0;
  if (blockIdx.x == 94 && threadIdx.x < Hh){
    int t = threadIdx.x;
    float s = 0.f;
    for (int yy=0; yy<Hh; ++yy){ float d=(float)(yy-t); s += expf(-d*d*(1.0f/18.0f)); }
    ws[OFF_ROWW + t] = s;                 // full 1-D colsum (spatial norm)
  }
  if (blockIdx.x == 95 && threadIdx.x < TAPS){
    int d = threadIdx.x - RAD;
    ws[OFF_WTAB + threadIdx.x] = expf(-(float)(d*d)*(1.0f/18.0f));
  }
}

// B: color histogram
__global__ __launch_bounds__(256) void prepB_kernel(const float* __restrict__ image,
                                                    float* __restrict__ ws){
  int n = blockIdx.x*256 + threadIdx.x;
  int key = color_key(image[n], image[NPIX+n], image[2*NPIX+n]);
  atomicAdd((int*)ws + OFF_HIST + key, 1);
}

// C: exclusive scan of 4096 bins (1 block)
__global__ __launch_bounds__(256) void prepC_kernel(float* __restrict__ ws){
  __shared__ int part[256];
  const int* hist = (const int*)ws + OFF_HIST;
  int* base = (int*)ws + OFF_BASE;
  int t = threadIdx.x;
  int loc[16]; int s = 0;
  #pragma unroll
  for (int i=0;i<16;i++){ loc[i]=s; s += hist[t*16+i]; }
  part[t] = s; __syncthreads();
  for (int off=1; off<256; off<<=1){
    int v = (t>=off) ? part[t-off] : 0;
    __syncthreads(); part[t] += v; __syncthreads();
  }
  int b = (t==0)?0:part[t-1];
  #pragma unroll
  for (int i=0;i<16;i++) base[t*16+i] = b + loc[i];
}

// D: scatter + sorted feature build (q in F slot 6) + initial q (orig + sorted)
__global__ __launch_bounds__(256) void prepD_kernel(const float* __restrict__ image,
                                                    const float* __restrict__ logits,
                                                    float* __restrict__ ws){
  int n = blockIdx.x*256 + threadIdx.x;
  int* W = (int*)ws;
  float r=image[n], g=image[NPIX+n], bl=image[2*NPIX+n];
  int key = color_key(r,g,bl);
  int pos = atomicAdd(W + OFF_BASE + key, 1);
  W[OFF_INV + n] = pos;
  W[OFF_SRT + pos] = n;
  int y=n/Ww, x=n%Ww;
  const float c=0.7213475205f;    // 0.5/ln2
  const float sc=1.2011224088f;   // sqrt(2c)
  float f0=(float)y*(1.f/160.f), f1=(float)x*(1.f/160.f);
  float f2=r*(1.f/3.f), f3=g*(1.f/3.f), f4=bl*(1.f/3.f);
  float a=c*(f0*f0+f1*f1+f2*f2+f3*f3+f4*f4);
  float q = 1.f/(1.f + __builtin_amdgcn_exp2f((logits[NPIX+n]-logits[n])*LOG2E));
  float* F = ws + OFF_F + (size_t)pos*8;
  F[0]=sc*f0; F[1]=sc*f1; F[2]=sc*f2; F[3]=sc*f3; F[4]=sc*f4;
  F[5]=a; F[6]=q; F[7]=0.f;
  ws[OFF_Q0 + n] = q;
  ws[OFF_QS + pos] = q;
}

// E1: per-chunk 5-D bbox, one wave per chunk
__global__ __launch_bounds__(256) void prepE1_kernel(float* __restrict__ ws){
  const int lane = threadIdx.x & 63, wid = threadIdx.x >> 6;
  int ch = blockIdx.x*4 + wid;
  if (ch >= NCH) return;
  const float* Fp = ws + OFF_F + ((size_t)ch*64 + lane)*8;
  float4 A = *(const float4*)Fp;
  float4 B4 = *(const float4*)(Fp+4);
  float mn[5]={A.x,A.y,A.z,A.w,B4.x}, mx[5]={A.x,A.y,A.z,A.w,B4.x};
  #pragma unroll
  for (int m=32; m; m>>=1){
    #pragma unroll
    for (int d=0;d<5;d++){
      mn[d]=fminf(mn[d], __shfl_xor(mn[d], m));
      mx[d]=fmaxf(mx[d], __shfl_xor(mx[d], m));
    }
  }
  if (lane == 0){
    float* bb = ws + OFF_BBOX + ch*12;
    #pragma unroll
    for (int d=0;d<5;d++){ bb[d]=mn[d]; bb[5+d]=mx[d]; }
  }
}

// E2: cull (box-box) + scan + pack flat worklist (1 block, all LDS)
__global__ __launch_bounds__(256) void prepE2_kernel(float* __restrict__ ws){
  __shared__ float bbl[NCH*12];
  __shared__ int part[256];
  __shared__ int cnt[NCH];
  const int t = threadIdx.x, lane = t & 63, wid = t >> 6;
  int* W = (int*)ws;

  for (int i=t; i<NCH*12; i+=256) bbl[i] = ws[OFF_BBOX + i];
  __syncthreads();

  for (int jg = wid; jg < NCH; jg += 4){
    const float* jb = &bbl[jg*12];
    int base = 0;
    #pragma unroll
    for (int r2=0;r2<3;r2++){
      int c2 = lane + 64*r2;
      bool sv = false;
      if (c2 < NCH){
        const float* cb = &bbl[c2*12];
        float s2 = 0.f;
        #pragma unroll
        for (int d=0;d<5;d++){
          float gap = fmaxf(0.f, fmaxf(cb[d]-jb[5+d], jb[d]-cb[5+d]));
          s2 = fmaf(gap, gap, s2);
        }
        sv = (s2 <= CUT2);
      }
      base += __popcll(__ballot(sv));
    }
    if (lane == 0) cnt[jg] = base;
  }
  __syncthreads();

  int v = (t < NCH) ? cnt[t] : 0;
  part[t] = v; __syncthreads();
  for (int off=1; off<256; off<<=1){
    int u = (t>=off) ? part[t-off] : 0;
    __syncthreads(); part[t] += u; __syncthreads();
  }
  if (t == 0) W[OFF_OFS] = 0;
  if (t < NCH) W[OFF_OFS + t + 1] = part[t];
  __syncthreads();

  for (int jg = wid; jg < NCH; jg += 4){
    const float* jb = &bbl[jg*12];
    int base = (jg == 0) ? 0 : part[jg-1];
    #pragma unroll
    for (int r2=0;r2<3;r2++){
      int c2 = lane + 64*r2;
      bool sv = false;
      if (c2 < NCH){
        const float* cb = &bbl[c2*12];
        float s2 = 0.f;
        #pragma unroll
        for (int d=0;d<5;d++){
          float gap = fmaxf(0.f, fmaxf(cb[d]-jb[5+d], jb[d]-cb[5+d]));
          s2 = fmaf(gap, gap, s2);
        }
        sv = (s2 <= CUT2);
      }
      unsigned long long m = __ballot(sv);
      if (sv){
        int pos = __popcll(m & ((1ull<<lane)-1ull));
        W[OFF_WORK + base + pos] = (jg<<8) | c2;
      }
      base += __popcll(m);
    }
  }
}

// buildK: 1024 waves, each owns a contiguous item segment, 2-deep pipelined:
// item n+1's global loads issue during item n's compute. q_i from staged w1.z.
// Packs fp16 K[item][j][i]; per-item coalesced atomics into sorted BV/CBI.
__global__ __launch_bounds__(256) void buildK_kernel(float* __restrict__ ws){
  __shared__ float chunk[4][512];
  const int lane = threadIdx.x & 63, wid = threadIdx.x >> 6;
  int* W = (int*)ws;
  const int T = W[OFF_OFS + NCH];
  const int* work = W + OFF_WORK;
  const float* F  = ws + OFF_F;
  float* s = &chunk[wid][0];
  const int NW = GRIDK*4;
  const int wv = blockIdx.x*4 + wid;
  const int seg = (T + NW - 1)/NW;
  int it = wv*seg;
  const int itEnd = min(T, it + seg);
  if (it >= itEnd) return;

  // prologue: item `it`
  int en = work[it];
  int c = en & 255;
  float4 rA = *(const float4*)(F + (size_t)c*512 + lane*8);
  float4 rB = *(const float4*)(F + (size_t)c*512 + lane*8 + 4);
  int js = (en >> 8)*64 + lane;
  float4 jA = *(const float4*)(F + (size_t)js*8);
  float4 jB = *(const float4*)(F + (size_t)js*8 + 4);

  for (;;){
    *(float4*)(s + lane*8)     = rA;
    *(float4*)(s + lane*8 + 4) = rB;
    const float h0=jA.x,h1=jA.y,h2=jA.z,h3=jA.w,h4=jB.x,na=-jB.y;
    const int curIt = it, curJs = js;

    // prefetch next item (issues before compute; waits land after)
    int nit = it + 1;
    bool more = nit < itEnd;
    float4 nA, nB, njA, njB; int njs = 0;
    if (more){
      int en2 = work[nit];
      int c2 = en2 & 255;
      nA = *(const float4*)(F + (size_t)c2*512 + lane*8);
      nB = *(const float4*)(F + (size_t)c2*512 + lane*8 + 4);
      njs = (en2 >> 8)*64 + lane;
      njA = *(const float4*)(F + (size_t)njs*8);
      njB = *(const float4*)(F + (size_t)njs*8 + 4);
    }

    float aB=0.f, aC=0.f;
    unsigned int kp[32];
    #pragma unroll
    for (int ii=0; ii<32; ii++){          // FULL unroll: kp indices constant
      float4 w0 = *(const float4*)(s + 2*ii*8);
      float4 w1 = *(const float4*)(s + 2*ii*8 + 4);
      float e0 = na - w1.y;
      e0=fmaf(h0,w0.x,e0); e0=fmaf(h1,w0.y,e0); e0=fmaf(h2,w0.z,e0);
      e0=fmaf(h3,w0.w,e0); e0=fmaf(h4,w1.x,e0);
      float k0 = __builtin_amdgcn_exp2f(e0);
      float4 u0 = *(const float4*)(s + (2*ii+1)*8);
      float4 u1 = *(const float4*)(s + (2*ii+1)*8 + 4);
      float e1 = na - u1.y;
      e1=fmaf(h0,u0.x,e1); e1=fmaf(h1,u0.y,e1); e1=fmaf(h2,u0.z,e1);
      e1=fmaf(h3,u0.w,e1); e1=fmaf(h4,u1.x,e1);
      float k1 = __builtin_amdgcn_exp2f(e1);
      aC += k0 + k1;
      aB = fmaf(k0, w1.z, aB);            // q_i staged in slot 6
      aB = fmaf(k1, u1.z, aB);
      __half2 h2v = __floats2half2_rn(k0, k1);
      kp[ii] = *reinterpret_cast<unsigned int*>(&h2v);
    }
    unsigned int* Kp = (unsigned int*)ws + OFF_K + (size_t)curIt*2048 + lane*32;
    #pragma unroll
    for (int r=0;r<8;r++)
      *(uint4*)(Kp + r*4) = make_uint4(kp[4*r],kp[4*r+1],kp[4*r+2],kp[4*r+3]);
    atomicAdd(ws + OFF_BV  + curJs, aB);
    atomicAdd(ws + OFF_CBI + curJs, aC);

    if (!more) break;
    it = nit; js = njs; rA = nA; rB = nB; jA = njA; jB = njB;
  }
}

// matvec: same segment decomposition, 2-deep pipelined K/q prefetch.
// Named p0..p7 regs (no runtime-indexed arrays). Per-item coalesced atomic.
__global__ __launch_bounds__(256) void matvec_kernel(float* __restrict__ ws){
  __shared__ float qsh[4][64];
  const int lane = threadIdx.x & 63, wid = threadIdx.x >> 6;
  const int* W = (const int*)ws;
  const int T = W[OFF_OFS + NCH];
  const int* work = W + OFF_WORK;
  float* ql = &qsh[wid][0];
  const int NW = GRIDM*4;
  const int wv = blockIdx.x*4 + wid;
  const int seg = (T + NW - 1)/NW;
  int it = wv*seg;
  const int itEnd = min(T, it + seg);
  if (it >= itEnd) return;

  const unsigned int* Kbase = (const unsigned int*)ws + OFF_K;

  // prologue: item `it`
  int en = work[it];
  int c = en & 255;
  int js = (en >> 8)*64 + lane;
  float qv = ws[OFF_QS + c*64 + lane];
  const unsigned int* Kp = Kbase + (size_t)it*2048 + lane*32;
  uint4 p0 = *(const uint4*)(Kp);
  uint4 p1 = *(const uint4*)(Kp + 4);
  uint4 p2 = *(const uint4*)(Kp + 8);
  uint4 p3 = *(const uint4*)(Kp + 12);
  uint4 p4 = *(const uint4*)(Kp + 16);
  uint4 p5 = *(const uint4*)(Kp + 20);
  uint4 p6 = *(const uint4*)(Kp + 24);
  uint4 p7 = *(const uint4*)(Kp + 28);

  for (;;){
    ql[lane] = qv;
    const int curJs = js;

    // prefetch next item
    int nit = it + 1;
    bool more = nit < itEnd;
    float nqv = 0.f; int njs = 0;
    uint4 n0,n1,n2,n3,n4,n5,n6,n7;
    if (more){
      int en2 = work[nit];
      int c2 = en2 & 255;
      njs = (en2 >> 8)*64 + lane;
      nqv = ws[OFF_QS + c2*64 + lane];
      const unsigned int* Np = Kbase + (size_t)nit*2048 + lane*32;
      n0=*(const uint4*)(Np);    n1=*(const uint4*)(Np+4);
      n2=*(const uint4*)(Np+8);  n3=*(const uint4*)(Np+12);
      n4=*(const uint4*)(Np+16); n5=*(const uint4*)(Np+20);
      n6=*(const uint4*)(Np+24); n7=*(const uint4*)(Np+28);
    }

    float acc0=0.f, acc1=0.f;
    #define MV_STEP(P, R)                                                      \
    {                                                                          \
      float4 qa = *(const float4*)(ql + (R)*8);                                \
      float4 qb = *(const float4*)(ql + (R)*8 + 4);                            \
      __half2 h;                                                               \
      h = *reinterpret_cast<__half2*>(&P.x);                                   \
      acc0 = fmaf(__low2float(h), qa.x, acc0);                                 \
      acc1 = fmaf(__high2float(h), qa.y, acc1);                                \
      h = *reinterpret_cast<__half2*>(&P.y);                                   \
      acc0 = fmaf(__low2float(h), qa.z, acc0);                                 \
      acc1 = fmaf(__high2float(h), qa.w, acc1);                                \
      h = *reinterpret_cast<__half2*>(&P.z);                                   \
      acc0 = fmaf(__low2float(h), qb.x, acc0);                                 \
      acc1 = fmaf(__high2float(h), qb.y, acc1);                                \
      h = *reinterpret_cast<__half2*>(&P.w);                                   \
      acc0 = fmaf(__low2float(h), qb.z, acc0);                                 \
      acc1 = fmaf(__high2float(h), qb.w, acc1);                                \
    }
    MV_STEP(p0,0) MV_STEP(p1,1) MV_STEP(p2,2) MV_STEP(p3,3)
    MV_STEP(p4,4) MV_STEP(p5,5) MV_STEP(p6,6) MV_STEP(p7,7)
    #undef MV_STEP

    atomicAdd(ws + OFF_BV + curJs, acc0 + acc1);

    if (!more) break;
    it = nit; js = njs; qv = nqv;
    p0=n0; p1=n1; p2=n2; p3=n3; p4=n4; p5=n5; p6=n6; p7=n7;
  }
}

// combine: separable spatial conv + message/compat/update + next-iter q.
__global__ __launch_bounds__(256) void combine_kernel(const float* __restrict__ logits,
                                                      const float* __restrict__ Wsp,
                                                      const float* __restrict__ Wbi,
                                                      const float* __restrict__ Cm,
                                                      float* __restrict__ ws,
                                                      float* __restrict__ out,
                                                      const float* __restrict__ qsrc,
                                                      float* __restrict__ qdst){
  __shared__ float tq[46][48];
  __shared__ float tr[46][17];
  __shared__ float wt[TAPS];
  int tx = threadIdx.x & 15, ty = threadIdx.x >> 4;
  int bx = blockIdx.x % 6, by = blockIdx.x / 6;
  int x0 = bx*16, y0 = by*16;

  for (int idx = threadIdx.x; idx < 46*46; idx += 256){
    int ly = idx / 46, lx = idx % 46;
    int gy = y0 - RAD + ly, gx = x0 - RAD + lx;
    float v = 0.f;
    if (gy >= 0 && gy < Hh && gx >= 0 && gx < Ww) v = qsrc[gy*Ww + gx];
    tq[ly][lx] = v;
  }
  if (threadIdx.x < TAPS) wt[threadIdx.x] = ws[OFF_WTAB + threadIdx.x];
  __syncthreads();

  for (int idx = threadIdx.x; idx < 46*16; idx += 256){
    int ly = idx >> 4, lx = idx & 15;
    float in = 0.f;
    #pragma unroll
    for (int dx=0; dx<TAPS; dx++) in = fmaf(wt[dx], tq[ly][lx+dx], in);
    tr[ly][lx] = in;
  }
  __syncthreads();

  int y = y0 + ty, x = x0 + tx, j = y*Ww + x;
  float S = 0.f;
  #pragma unroll
  for (int dy=0; dy<TAPS; dy++) S = fmaf(wt[dy], tr[ty+dy][tx], S);

  int js = ((const int*)ws)[OFF_INV + j];
  float Bv = ws[OFF_BV + js];
  ws[OFF_BV + js] = 0.f;                      // reset for next iteration's atomics
  float Cb = ws[OFF_CBI + js];
  float nb  = 1.0f/(Cb + EPSV);
  float Csp = ws[OFF_ROWW + y] * ws[OFF_ROWW + x];
  float nsp = 1.0f/(Csp + EPSV);

  float sp0 = S*nsp,  sp1 = (Csp - S)*nsp;    // q1 = 1 - q0 identity
  float bi0 = Bv*nb,  bi1 = (Cb - Bv)*nb;

  float m0 = Wsp[0]*sp0 + Wsp[1]*sp1 + Wbi[0]*bi0 + Wbi[1]*bi1;
  float m1 = Wsp[2]*sp0 + Wsp[3]*sp1 + Wbi[2]*bi0 + Wbi[3]*bi1;
  float cm0 = Cm[0]*m0 + Cm[1]*m1;
  float cm1 = Cm[2]*m0 + Cm[3]*m1;

  float o0 = logits[j]        - cm0;
  float o1 = logits[NPIX + j] - cm1;
  out[j]        = o0;
  out[NPIX + j] = o1;

  float qn = 1.0f / (1.0f + __builtin_amdgcn_exp2f((o1-o0)*LOG2E));
  qdst[j] = qn;
  ws[OFF_QS + js] = qn;
}

extern "C" void kernel_launch(void* const* d_in, const int* in_sizes, int n_in,
                              void* d_out, int out_size, void* d_ws, size_t ws_size,
                              hipStream_t stream){
  const float* image  = (const float*)d_in[0];
  const float* logits = (const float*)d_in[1];
  const float* Wsp    = (const float*)d_in[2];
  const float* Wbi    = (const float*)d_in[3];
  const float* Cm     = (const float*)d_in[4];
  float* out = (float*)d_out;
  float* ws  = (float*)d_ws;

  float* qbuf[2] = { ws + OFF_Q0, ws + OFF_Q1 };

  prepA_kernel <<<96, 256, 0, stream>>>(ws);
  prepB_kernel <<<36, 256, 0, stream>>>(image, ws);
  prepC_kernel <<<1, 256, 0, stream>>>(ws);
  prepD_kernel <<<36, 256, 0, stream>>>(image, logits, ws);
  prepE1_kernel<<<36, 256, 0, stream>>>(ws);
  prepE2_kernel<<<1, 256, 0, stream>>>(ws);

  // iteration 0: build fp16 K + colsum + q-filter in one pass
  buildK_kernel<<<GRIDK, 256, 0, stream>>>(ws);
  combine_kernel<<<36, 256, 0, stream>>>(logits, Wsp, Wbi, Cm, ws, out,
                                         qbuf[0], qbuf[1]);
  // iterations 1..4: stream K
  for (int t=1; t<5; ++t){
    matvec_kernel<<<GRIDM, 256, 0, stream>>>(ws);
    combine_kernel<<<36, 256, 0, stream>>>(logits, Wsp, Wbi, Cm, ws, out,
                                           qbuf[t&1], qbuf[(t+1)&1]);
  }
}